// Round 3
// baseline (185.392 us; speedup 1.0000x reference)
//
#include <hip/hip_runtime.h>
#include <hip/hip_cooperative_groups.h>

namespace cg = cooperative_groups;

// ---------------------------------------------------------------------------
// Algebraic collapse of the whole model:
//   X[b, s, p]  = x[b, 0, ti*64+pr, tk*64+pc],  s = 8*ti+tk, p = 64*pr+pc
//   scores[b,h,i,j] ~ A'_h * G[b,i,j] + Bk'_h * sX[b,j]   (+ j-const terms
//                     that cancel in softmax);  G = token Gram of raw X
//   out[b,i,p] = sum_j W[b,i,j] * X[b,j,p] + const0,
//   W[b,i,j]   = sum_h g_h * softmax_j(scores)_h
//
// R11: R10 failed to compile (local `b2` shadowed the `b2` bias parameter).
// Renamed to `bq`. Structure unchanged from R10: k1+k2 fused into ONE
// cooperative kernel (256 blocks = 1/CU, co-resident) with __threadfence()
// + grid.sync() replacing the kernel boundary; k3 unchanged.
// If this is neutral vs R9's 88.8us, we are at the harness floor.
// ---------------------------------------------------------------------------

#define CONST_OFF 0                       // 16 floats: c0 at [12]
#define SXP_OFF   16                      // 256*64 partial token sums
#define WB_OFF    (16 + 256*64)           // W bf16 [b][i][j]: 8*4096 ushort = 16384 floats
#define PART_OFF  (WB_OFF + 8*2048)       // partial Grams: [256 blocks][4096] fp32

typedef __attribute__((ext_vector_type(8))) short bf16x8;
typedef __attribute__((ext_vector_type(4))) float f32x4;

__device__ __forceinline__ unsigned short f2bf(float f) {
    unsigned int u = __float_as_uint(f);
    u = (u + 0x7FFFu + ((u >> 16) & 1u)) >> 16;   // RNE
    return (unsigned short)u;
}

// ---------------------------------------------------------------------------
// K12 (cooperative): part 1 = partial Gram via MFMA, 256 blocks
// (8 b x 32 prg2) x 256 threads, each block covers 2 pr-rows (K=128).
// threadfence + grid.sync, then blocks 0..63 run the old k2 (weight
// contraction, G/sx reduction, softmax, W -> bf16).
// ---------------------------------------------------------------------------
__global__ __launch_bounds__(256) void k12_gram_attn(
    const float* __restrict__ x,
    const float* __restrict__ w1, const float* __restrict__ b1,
    const float* __restrict__ wqkv, const float* __restrict__ wproj,
    const float* __restrict__ bproj, const float* __restrict__ w2,
    const float* __restrict__ b2, float* __restrict__ ws)
{
    __shared__ unsigned short xsb[64 * 136];
    // k2-part LDS (disjoint from xsb; ~22 KB total, 1 block/CU)
    __shared__ float arow[96], crow[96], pvec[32];
    __shared__ float cst[16];
    __shared__ float G_s[8 * 65];
    __shared__ float sxp_s[4][64];
    __shared__ float sx_s[64];
    __shared__ float coef_s[4][8];
    __shared__ float m_s[4][8];

    int bid = blockIdx.x;
    int b = bid >> 5, prg2 = bid & 31;
    int t = threadIdx.x;
    const float* xb = x + (size_t)b * 262144;

    // ---- part 1: gram partials (identical arithmetic to R9 k1) ----
    float4 v[8];
    #pragma unroll
    for (int u = 0; u < 8; ++u) {
        int q = t + 256 * u;              // float4 index within 2x512 rows x 8 tj
        int prl = q >> 10, rem = q & 1023;
        int tj = rem >> 7, col4 = rem & 127;
        v[u] = *(const float4*)(xb + (tj * 64 + prg2 * 2 + prl) * 512 + col4 * 4);
    }
    #pragma unroll
    for (int u = 0; u < 8; ++u) {
        int q = t + 256 * u;
        int prl = q >> 10, rem = q & 1023;
        int tj = rem >> 7, col4 = rem & 127;
        int token = tj * 8 + (col4 >> 4);
        ushort4 h;
        h.x = f2bf(v[u].x); h.y = f2bf(v[u].y); h.z = f2bf(v[u].z); h.w = f2bf(v[u].w);
        *(ushort4*)(&xsb[token * 136 + prl * 64 + (col4 & 15) * 4]) = h;
    }
    __syncthreads();

    // token-sum contribution of this K-chunk (from bf16 values; err ~1e-7)
    if (t < 64) {
        const uint4* p = (const uint4*)(&xsb[t * 136]);
        float s = 0.f;
        #pragma unroll
        for (int c = 0; c < 16; ++c) {    // 16 x 8 bf16 = 128 values
            uint4 u = p[c];
            s += __uint_as_float(u.x << 16) + __uint_as_float(u.x & 0xFFFF0000u)
               + __uint_as_float(u.y << 16) + __uint_as_float(u.y & 0xFFFF0000u)
               + __uint_as_float(u.z << 16) + __uint_as_float(u.z & 0xFFFF0000u)
               + __uint_as_float(u.w << 16) + __uint_as_float(u.w & 0xFFFF0000u);
        }
        ws[SXP_OFF + bid * 64 + t] = s;
    }

    {
        int w = t >> 6, lane = t & 63;
        int m = lane & 15, quad = lane >> 4;
        f32x4 acc[4];
        #pragma unroll
        for (int jq = 0; jq < 4; ++jq) acc[jq] = (f32x4){0.f, 0.f, 0.f, 0.f};

        #pragma unroll
        for (int s = 0; s < 4; ++s) {     // K=128 -> 4 k-steps
            int kb = s * 32 + quad * 8;
            bf16x8 a = *(const bf16x8*)(&xsb[(w * 16 + m) * 136 + kb]);
            #pragma unroll
            for (int jq = 0; jq < 4; ++jq) {
                bf16x8 bb = *(const bf16x8*)(&xsb[(jq * 16 + m) * 136 + kb]);
                acc[jq] = __builtin_amdgcn_mfma_f32_16x16x32_bf16(a, bb, acc[jq],
                                                                  0, 0, 0);
            }
        }

        // C/D layout (m89): col = lane&15 (j), row = (lane>>4)*4 + reg (i)
        float* part = ws + PART_OFF + (size_t)bid * 4096;
        #pragma unroll
        for (int jq = 0; jq < 4; ++jq)
            #pragma unroll
            for (int r = 0; r < 4; ++r)
                part[(w * 16 + quad * 4 + r) * 64 + jq * 16 + m] = acc[jq][r];
    }

    // ---- device-scope hand-off (replaces the k1->k2 kernel boundary) ----
    __threadfence();
    cg::this_grid().sync();

    if (bid >= 64) return;
    __threadfence();                      // consumer-side acquire

    int bq = bid >> 3, rg = bid & 7;

    // phase 0a: per-output-row contractions of wqkv with w1/b1, w2.wproj
    if (t < 96) {
        float sa = 0.f, sc = 0.f;
        for (int c = 0; c < 32; ++c) {
            float w = wqkv[t * 32 + c];
            sa += w * w1[c];
            sc += w * b1[c];
        }
        arow[t] = sa; crow[t] = sc;
    } else if (t < 128) {
        int c = t - 96;
        float s = 0.f;
        for (int oc = 0; oc < 32; ++oc) s += w2[oc] * wproj[oc * 32 + c];
        pvec[c] = s;
    }

    // phase 1a: reduce this block's 8 G-rows over 32 partials (coalesced)
    {
        const float* p0 = ws + PART_OFF + (size_t)(bq * 32) * 4096 + rg * 512;
        float a0 = 0.f, a1 = 0.f;
        #pragma unroll
        for (int r = 0; r < 32; ++r) {
            const float* pr = p0 + (size_t)r * 4096;
            a0 += pr[t]; a1 += pr[t + 256];
        }
        int e0 = t;          G_s[(e0 >> 6) * 65 + (e0 & 63)] = a0;
        int e1 = t + 256;    G_s[(e1 >> 6) * 65 + (e1 & 63)] = a1;
    }

    // phase 1b: reduce partial token sums (32 x 64 -> 64)
    {
        int j = t & 63, r4 = t >> 6;     // r4 in [0,4)
        float s = 0.f;
        #pragma unroll
        for (int k = 0; k < 8; ++k)
            s += ws[SXP_OFF + (bq * 32 + r4 * 8 + k) * 64 + j];
        sxp_s[r4][j] = s;
    }
    __syncthreads();
    if (t < 64)
        sx_s[t] = sxp_s[0][t] + sxp_s[1][t] + sxp_s[2][t] + sxp_s[3][t];

    // phase 0b: combine into the 13 scalars
    const float scale = 1.0f / (4096.0f * 2.8284271247461903f); // 1/(P*sqrt(d))
    if (t >= 64 && t < 68) {
        int h = t - 64;
        float A = 0.f, Bk = 0.f, g = 0.f;
        #pragma unroll
        for (int dd = 0; dd < 8; ++dd) {
            int o = h * 8 + dd;
            A  += arow[o] * arow[32 + o];   // aq . ak
            Bk += crow[o] * arow[32 + o];   // cq . ak
            g  += pvec[o] * arow[64 + o];   // pvec . av
        }
        cst[h]     = A * scale;
        cst[4 + h] = Bk * scale;
        cst[8 + h] = g;
    } else if (t == 68) {
        float c0v = b2[0];
        for (int c = 0; c < 32; ++c)  c0v += pvec[c] * crow[64 + c];
        for (int oc = 0; oc < 32; ++oc) c0v += w2[oc] * bproj[oc];
        cst[12] = c0v;
    }
    __syncthreads();

    // phase 2a: softmax stats, 8 lanes per (head, local-row) pair
    {
        int pair = t >> 3, jg = t & 7;   // pair in [0,32)
        int h = pair >> 3, il = pair & 7;
        float A  = cst[h];
        float Bk = cst[4 + h];
        float sv[8];
        float mloc = -1e30f;
        #pragma unroll
        for (int jj = 0; jj < 8; ++jj) {
            int j = jg * 8 + jj;
            float s = A * G_s[il * 65 + j] + Bk * sx_s[j];
            sv[jj] = s;
            mloc = fmaxf(mloc, s);
        }
        mloc = fmaxf(mloc, __shfl_xor(mloc, 1));
        mloc = fmaxf(mloc, __shfl_xor(mloc, 2));
        mloc = fmaxf(mloc, __shfl_xor(mloc, 4));
        float z = 0.f;
        #pragma unroll
        for (int jj = 0; jj < 8; ++jj) z += __expf(sv[jj] - mloc);
        z += __shfl_xor(z, 1);
        z += __shfl_xor(z, 2);
        z += __shfl_xor(z, 4);
        if (jg == 0) {
            coef_s[h][il] = cst[8 + h] / z;
            m_s[h][il]    = mloc;
        }
    }
    __syncthreads();

    // phase 2b: 512 W entries as bf16 (row-major [i][j])
    {
        float A0 = cst[0], A1 = cst[1], A2 = cst[2], A3 = cst[3];
        float B0 = cst[4], B1 = cst[5], B2 = cst[6], B3 = cst[7];
        unsigned short* wout =
            (unsigned short*)(ws + WB_OFF) + bq * 4096 + rg * 512;
        #pragma unroll
        for (int k = 0; k < 2; ++k) {
            int e = t + 256 * k;          // local flat index il*64+j
            int il = e >> 6, j = e & 63;
            float G  = G_s[il * 65 + j];
            float sx = sx_s[j];
            float w =
                coef_s[0][il] * __expf(A0 * G + B0 * sx - m_s[0][il]) +
                coef_s[1][il] * __expf(A1 * G + B1 * sx - m_s[1][il]) +
                coef_s[2][il] * __expf(A2 * G + B2 * sx - m_s[2][il]) +
                coef_s[3][il] * __expf(A3 * G + B3 * sx - m_s[3][il]);
            wout[e] = f2bf(w);
        }
    }
    if (bid == 0 && t == 68) ws[CONST_OFF + 12] = cst[12];
}

// ---------------------------------------------------------------------------
// K3: out[b, i, pr, c] = const0 + sum_j W[b,i,j] * X[b,j,(pr,c)] via MFMA.
// 512 blocks (b x pr) x 256 threads. Unchanged from R9 (verified).
// ---------------------------------------------------------------------------
__global__ __launch_bounds__(256) void k3_apply(const float* __restrict__ x,
                                                const float* __restrict__ ws,
                                                float* __restrict__ out)
{
    __shared__ unsigned short xt[64 * 72];   // [c][j], j-groups swizzled
    __shared__ unsigned short wsm[64 * 72];  // [i][j]
    int b = blockIdx.x >> 6, pr = blockIdx.x & 63;
    int t = threadIdx.x;
    const float* xb = x + (size_t)b * 262144;

    // issue all global loads first (W from L2, x from L3/HBM)
    const uint4* wb = (const uint4*)((const unsigned short*)(ws + WB_OFF)
                                     + b * 4096);
    uint4 wv[2];
    #pragma unroll
    for (int k = 0; k < 2; ++k) wv[k] = wb[t + 256 * k];

    float4 v[4];
    #pragma unroll
    for (int k = 0; k < 4; ++k) {
        int q = t + 256 * k;              // float4 idx in [0,1024)
        int j = q >> 4, c4 = q & 15;      // token j, float4-within-row c4
        int ti = j >> 3, tk = j & 7;
        v[k] = *(const float4*)(xb + (ti * 64 + pr) * 512 + tk * 64 + c4 * 4);
    }

    #pragma unroll
    for (int k = 0; k < 4; ++k) {
        int q = t + 256 * k;
        int j = q >> 4, c4 = q & 15;
        int jx = j ^ ((c4 & 7) << 3);     // swizzle token-group by (c>>2)&7
        xt[(4 * c4 + 0) * 72 + jx] = f2bf(v[k].x);
        xt[(4 * c4 + 1) * 72 + jx] = f2bf(v[k].y);
        xt[(4 * c4 + 2) * 72 + jx] = f2bf(v[k].z);
        xt[(4 * c4 + 3) * 72 + jx] = f2bf(v[k].w);
    }
    {   // W: 4096 ushort = 512 uint4 (8 ushorts each); q in [0,512)
        #pragma unroll
        for (int k = 0; k < 2; ++k) {
            int q = t + 256 * k;
            int i = q >> 3, j8 = q & 7;   // flat = q*8 = i*64 + j8*8
            *(uint4*)(&wsm[i * 72 + j8 * 8]) = wv[k];
        }
    }
    __syncthreads();

    int w = t >> 6, lane = t & 63;
    int m = lane & 15, quad = lane >> 4;
    f32x4 acc[4];
    #pragma unroll
    for (int jq = 0; jq < 4; ++jq) acc[jq] = (f32x4){0.f, 0.f, 0.f, 0.f};

    #pragma unroll
    for (int s = 0; s < 2; ++s) {
        int kb = s * 32 + quad * 8;
        bf16x8 a = *(const bf16x8*)(&wsm[(w * 16 + m) * 72 + kb]);   // W[i][k]
        #pragma unroll
        for (int jq = 0; jq < 4; ++jq) {
            int row = jq * 16 + m;
            int kbx = kb ^ (((row >> 2) & 7) << 3);                  // match swizzle
            bf16x8 bv = *(const bf16x8*)(&xt[row * 72 + kbx]);       // X^T[c][k]
            acc[jq] = __builtin_amdgcn_mfma_f32_16x16x32_bf16(a, bv, acc[jq],
                                                              0, 0, 0);
        }
    }

    float c0 = ws[CONST_OFF + 12];
    float* ob = out + (size_t)b * 262144;
    // D row = i (A's row), D col = c (B's row): col=lane&15, row=quad*4+r
    #pragma unroll
    for (int jq = 0; jq < 4; ++jq)
        #pragma unroll
        for (int r = 0; r < 4; ++r) {
            int i = w * 16 + quad * 4 + r;
            int c = jq * 16 + m;
            int ti = i >> 3, tk = i & 7;
            ob[(ti * 64 + pr) * 512 + tk * 64 + c] = acc[jq][r] + c0;
        }
}

extern "C" void kernel_launch(void* const* d_in, const int* in_sizes, int n_in,
                              void* d_out, int out_size, void* d_ws, size_t ws_size,
                              hipStream_t stream) {
    const float* x     = (const float*)d_in[0];
    // d_in[1] = n, d_in[2] = m  (fixed 8 by setup_inputs)
    const float* w1    = (const float*)d_in[3];
    const float* b1    = (const float*)d_in[4];
    const float* wqkv  = (const float*)d_in[5];
    const float* wproj = (const float*)d_in[6];
    const float* bproj = (const float*)d_in[7];
    const float* w2    = (const float*)d_in[8];
    const float* b2    = (const float*)d_in[9];
    float* out = (float*)d_out;
    float* ws  = (float*)d_ws;

    void* args[] = {(void*)&x, (void*)&w1, (void*)&b1, (void*)&wqkv,
                    (void*)&wproj, (void*)&bproj, (void*)&w2, (void*)&b2,
                    (void*)&ws};
    (void)hipLaunchCooperativeKernel((const void*)k12_gram_attn, dim3(256),
                                     dim3(256), args, 0, stream);
    k3_apply<<<512, 256, 0, stream>>>(x, ws, out);
}

// Round 4
// 88.764 us; speedup vs baseline: 2.0886x; 2.0886x over previous
//
#include <hip/hip_runtime.h>

// ---------------------------------------------------------------------------
// Algebraic collapse of the whole model:
//   X[b, s, p]  = x[b, 0, ti*64+pr, tk*64+pc],  s = 8*ti+tk, p = 64*pr+pc
//   scores[b,h,i,j] ~ A'_h * G[b,i,j] + Bk'_h * sX[b,j]   (+ j-const terms
//                     that cancel in softmax);  G = token Gram of raw X
//   out[b,i,p] = sum_j W[b,i,j] * X[b,j,p] + const0,
//   W[b,i,j]   = sum_h g_h * softmax_j(scores)_h
//
// R12: REVERT to the R0 best (87.7us). History: R9 (k1 occupancy 2x, k2
// wave-parallel softmax, k3 swizzle) was neutral (88.8); R10/R11
// cooperative k1+k2 fusion regressed hard (185us — cooperative launch is
// not graph-replay friendly in this harness). Conclusion: the iteration is
// floor-dominated by the harness's ~41us ws-poison fill (itself at 82% of
// HBM peak) + fixed dispatch overhead; our three kernels are individually
// shorter than the fill and insensitive to further in-kernel optimization.
// ---------------------------------------------------------------------------

#define CONST_OFF 0                       // 16 floats: c0 at [12]
#define SXP_OFF   16                      // 128*64 partial token sums
#define WB_OFF    (16 + 128*64)           // W bf16 [b][i][j]: 8*4096 ushort = 16384 floats
#define PART_OFF  (WB_OFF + 8*2048)       // partial Grams: [128 blocks][4096] fp32

typedef __attribute__((ext_vector_type(8))) short bf16x8;
typedef __attribute__((ext_vector_type(4))) float f32x4;

__device__ __forceinline__ unsigned short f2bf(float f) {
    unsigned int u = __float_as_uint(f);
    u = (u + 0x7FFFu + ((u >> 16) & 1u)) >> 16;   // RNE
    return (unsigned short)u;
}

// ---------------------------------------------------------------------------
// K1: partial Gram via MFMA. 128 blocks (8 b x 16 prg) x 256 threads.
// Stage x as bf16 into xsb[token][k], row stride 272 bf16 (2-way bank
// aliasing = free). 4 waves x 4 j-tiles x 8 K-steps of mfma_16x16x32_bf16.
// ---------------------------------------------------------------------------
__global__ __launch_bounds__(256) void k1_gram(const float* __restrict__ x,
                                               float* __restrict__ ws)
{
    __shared__ unsigned short xsb[64 * 272];
    int b = blockIdx.x >> 4, prg = blockIdx.x & 15;
    int t = threadIdx.x;
    const float* xb = x + (size_t)b * 262144;

    #pragma unroll
    for (int prl = 0; prl < 4; ++prl) {
        int pr = prg * 4 + prl;
        #pragma unroll
        for (int k = 0; k < 4; ++k) {
            int q = t + 256 * k;          // float4 index within 8x512 rows
            int tj = q >> 7, col4 = q & 127;
            float4 v = *(const float4*)(xb + (tj * 64 + pr) * 512 + col4 * 4);
            int token = tj * 8 + (col4 >> 4);
            ushort4 h;
            h.x = f2bf(v.x); h.y = f2bf(v.y); h.z = f2bf(v.z); h.w = f2bf(v.w);
            *(ushort4*)(&xsb[token * 272 + prl * 64 + (col4 & 15) * 4]) = h;
        }
    }
    __syncthreads();

    // token-sum contribution of this K-chunk (from bf16 values; err ~1e-7)
    if (t < 64) {
        const uint4* p = (const uint4*)(&xsb[t * 272]);
        float s = 0.f;
        #pragma unroll
        for (int c = 0; c < 32; ++c) {    // 32 x 8 bf16 = 256 values
            uint4 u = p[c];
            s += __uint_as_float(u.x << 16) + __uint_as_float(u.x & 0xFFFF0000u)
               + __uint_as_float(u.y << 16) + __uint_as_float(u.y & 0xFFFF0000u)
               + __uint_as_float(u.z << 16) + __uint_as_float(u.z & 0xFFFF0000u)
               + __uint_as_float(u.w << 16) + __uint_as_float(u.w & 0xFFFF0000u);
        }
        ws[SXP_OFF + blockIdx.x * 64 + t] = s;
    }

    int w = t >> 6, lane = t & 63;
    int m = lane & 15, quad = lane >> 4;
    f32x4 acc[4];
    #pragma unroll
    for (int jq = 0; jq < 4; ++jq) acc[jq] = (f32x4){0.f, 0.f, 0.f, 0.f};

    #pragma unroll
    for (int s = 0; s < 8; ++s) {
        int kb = s * 32 + quad * 8;
        bf16x8 a = *(const bf16x8*)(&xsb[(w * 16 + m) * 272 + kb]);
        #pragma unroll
        for (int jq = 0; jq < 4; ++jq) {
            bf16x8 bb = *(const bf16x8*)(&xsb[(jq * 16 + m) * 272 + kb]);
            acc[jq] = __builtin_amdgcn_mfma_f32_16x16x32_bf16(a, bb, acc[jq],
                                                              0, 0, 0);
        }
    }

    // C/D layout (m89): col = lane&15 (j), row = (lane>>4)*4 + reg (i)
    float* part = ws + PART_OFF + (size_t)blockIdx.x * 4096;
    #pragma unroll
    for (int jq = 0; jq < 4; ++jq)
        #pragma unroll
        for (int r = 0; r < 4; ++r)
            part[(w * 16 + quad * 4 + r) * 64 + jq * 16 + m] = acc[jq][r];
}

// ---------------------------------------------------------------------------
// K2: 64 blocks (b x row-group rg of 8 rows) x 256 threads:
//   phase 0: contract weights -> 13 scalars (redundant per block, trivial)
//   phase 1: reduce this block's 8 G-rows (16 partials x 512 floats) + sx
//   phase 2a: softmax (m, Z) for 32 (head,row) pairs
//   phase 2b: W[i][j] -> global as bf16 (k3 stages it raw)
// ---------------------------------------------------------------------------
__global__ __launch_bounds__(256) void k2_attn(
    const float* __restrict__ w1, const float* __restrict__ b1,
    const float* __restrict__ wqkv, const float* __restrict__ wproj,
    const float* __restrict__ bproj, const float* __restrict__ w2,
    const float* __restrict__ b2, float* __restrict__ ws)
{
    __shared__ float arow[96], crow[96], pvec[32];
    __shared__ float cst[16];
    __shared__ float G_s[8 * 65];        // 8 local rows, pad 65
    __shared__ float sxp_s[4][64];
    __shared__ float sx_s[64];
    __shared__ float coef_s[4][8];
    __shared__ float m_s[4][8];
    int b = blockIdx.x >> 3, rg = blockIdx.x & 7;
    int t = threadIdx.x;

    // phase 0a: per-output-row contractions of wqkv with w1/b1, w2.wproj
    if (t < 96) {
        float sa = 0.f, sc = 0.f;
        for (int c = 0; c < 32; ++c) {
            float w = wqkv[t * 32 + c];
            sa += w * w1[c];
            sc += w * b1[c];
        }
        arow[t] = sa; crow[t] = sc;
    } else if (t < 128) {
        int c = t - 96;
        float s = 0.f;
        for (int oc = 0; oc < 32; ++oc) s += w2[oc] * wproj[oc * 32 + c];
        pvec[c] = s;
    }

    // phase 1a: reduce this block's 8 G-rows over 16 partials (coalesced)
    {
        const float* p0 = ws + PART_OFF + (size_t)(b * 16) * 4096 + rg * 512;
        float a0 = 0.f, a1 = 0.f;
        #pragma unroll
        for (int r = 0; r < 16; ++r) {
            const float* pr = p0 + (size_t)r * 4096;
            a0 += pr[t]; a1 += pr[t + 256];
        }
        int e0 = t;          G_s[(e0 >> 6) * 65 + (e0 & 63)] = a0;
        int e1 = t + 256;    G_s[(e1 >> 6) * 65 + (e1 & 63)] = a1;
    }

    // phase 1b: reduce partial token sums (16 x 64 -> 64)
    {
        int j = t & 63, r4 = t >> 6;     // r4 in [0,4)
        float s = 0.f;
        #pragma unroll
        for (int k = 0; k < 4; ++k)
            s += ws[SXP_OFF + (b * 16 + r4 * 4 + k) * 64 + j];
        sxp_s[r4][j] = s;
    }
    __syncthreads();
    if (t < 64)
        sx_s[t] = sxp_s[0][t] + sxp_s[1][t] + sxp_s[2][t] + sxp_s[3][t];

    // phase 0b: combine into the 13 scalars
    const float scale = 1.0f / (4096.0f * 2.8284271247461903f); // 1/(P*sqrt(d))
    if (t >= 64 && t < 68) {
        int h = t - 64;
        float A = 0.f, Bk = 0.f, g = 0.f;
        #pragma unroll
        for (int dd = 0; dd < 8; ++dd) {
            int o = h * 8 + dd;
            A  += arow[o] * arow[32 + o];   // aq . ak
            Bk += crow[o] * arow[32 + o];   // cq . ak
            g  += pvec[o] * arow[64 + o];   // pvec . av
        }
        cst[h]     = A * scale;
        cst[4 + h] = Bk * scale;
        cst[8 + h] = g;
    } else if (t == 68) {
        float c0 = b2[0];
        for (int c = 0; c < 32; ++c)  c0 += pvec[c] * crow[64 + c];
        for (int oc = 0; oc < 32; ++oc) c0 += w2[oc] * bproj[oc];
        cst[12] = c0;
    }
    __syncthreads();

    // phase 2a: softmax stats for 32 (head, local-row) pairs
    if (t < 32) {
        int h = t >> 3, il = t & 7;
        float A  = cst[h];
        float Bk = cst[4 + h];
        float g  = cst[8 + h];
        float m = -1e30f;
        for (int j = 0; j < 64; ++j) {
            float s = A * G_s[il * 65 + j] + Bk * sx_s[j];
            m = fmaxf(m, s);
        }
        float Z = 0.f;
        for (int j = 0; j < 64; ++j) {
            float s = A * G_s[il * 65 + j] + Bk * sx_s[j];
            Z += __expf(s - m);
        }
        coef_s[h][il] = g / Z;
        m_s[h][il]    = m;
    }
    __syncthreads();

    // phase 2b: 512 W entries as bf16 (row-major [i][j])
    {
        float A0 = cst[0], A1 = cst[1], A2 = cst[2], A3 = cst[3];
        float B0 = cst[4], B1 = cst[5], B2 = cst[6], B3 = cst[7];
        unsigned short* wout =
            (unsigned short*)(ws + WB_OFF) + b * 4096 + rg * 512;
        #pragma unroll
        for (int k = 0; k < 2; ++k) {
            int e = t + 256 * k;          // local flat index il*64+j
            int il = e >> 6, j = e & 63;
            float G  = G_s[il * 65 + j];
            float sx = sx_s[j];
            float w =
                coef_s[0][il] * __expf(A0 * G + B0 * sx - m_s[0][il]) +
                coef_s[1][il] * __expf(A1 * G + B1 * sx - m_s[1][il]) +
                coef_s[2][il] * __expf(A2 * G + B2 * sx - m_s[2][il]) +
                coef_s[3][il] * __expf(A3 * G + B3 * sx - m_s[3][il]);
            wout[e] = f2bf(w);
        }
    }
    if (b == 0 && rg == 0 && t == 68) ws[CONST_OFF + 12] = cst[12];
}

// ---------------------------------------------------------------------------
// K3: out[b, i, pr, c] = const0 + sum_j W[b,i,j] * X[b,j,(pr,c)] via MFMA.
// 512 blocks (b x pr) x 256 threads. Stage X^T[c][j] bf16 (LDS transpose,
// stride 72) and W[i][j] bf16 via uint4 copy (8 ushorts/op x 512 ops =
// full 4096-ushort matrix). K=64 -> 2 MFMA k-steps.
// ---------------------------------------------------------------------------
__global__ __launch_bounds__(256) void k3_apply(const float* __restrict__ x,
                                                const float* __restrict__ ws,
                                                float* __restrict__ out)
{
    __shared__ unsigned short xt[64 * 72];   // [c][j]
    __shared__ unsigned short wsm[64 * 72];  // [i][j]
    int b = blockIdx.x >> 6, pr = blockIdx.x & 63;
    int t = threadIdx.x;
    const float* xb = x + (size_t)b * 262144;

    #pragma unroll
    for (int k = 0; k < 4; ++k) {
        int q = t + 256 * k;              // float4 idx in [0,1024)
        int j = q >> 4, c4 = q & 15;      // token j, float4-within-row c4
        int ti = j >> 3, tk = j & 7;
        float4 v = *(const float4*)(xb + (ti * 64 + pr) * 512 + tk * 64 + c4 * 4);
        xt[(4 * c4 + 0) * 72 + j] = f2bf(v.x);
        xt[(4 * c4 + 1) * 72 + j] = f2bf(v.y);
        xt[(4 * c4 + 2) * 72 + j] = f2bf(v.z);
        xt[(4 * c4 + 3) * 72 + j] = f2bf(v.w);
    }
    {   // W: 4096 ushort = 512 uint4 (8 ushorts each); q in [0,512)
        const uint4* wb = (const uint4*)((const unsigned short*)(ws + WB_OFF)
                                         + b * 4096);
        #pragma unroll
        for (int k = 0; k < 2; ++k) {
            int q = t + 256 * k;
            int i = q >> 3, j8 = q & 7;   // flat = q*8 = i*64 + j8*8
            *(uint4*)(&wsm[i * 72 + j8 * 8]) = wb[q];
        }
    }
    __syncthreads();

    int w = t >> 6, lane = t & 63;
    int m = lane & 15, quad = lane >> 4;
    f32x4 acc[4];
    #pragma unroll
    for (int jq = 0; jq < 4; ++jq) acc[jq] = (f32x4){0.f, 0.f, 0.f, 0.f};

    #pragma unroll
    for (int s = 0; s < 2; ++s) {
        int kb = s * 32 + quad * 8;
        bf16x8 a = *(const bf16x8*)(&wsm[(w * 16 + m) * 72 + kb]);   // W[i][k]
        #pragma unroll
        for (int jq = 0; jq < 4; ++jq) {
            bf16x8 bv = *(const bf16x8*)(&xt[(jq * 16 + m) * 72 + kb]); // X^T[c][k]
            acc[jq] = __builtin_amdgcn_mfma_f32_16x16x32_bf16(a, bv, acc[jq],
                                                              0, 0, 0);
        }
    }

    float c0 = ws[CONST_OFF + 12];
    float* ob = out + (size_t)b * 262144;
    // D row = i (A's row), D col = c (B's row): col=lane&15, row=quad*4+r
    #pragma unroll
    for (int jq = 0; jq < 4; ++jq)
        #pragma unroll
        for (int r = 0; r < 4; ++r) {
            int i = w * 16 + quad * 4 + r;
            int c = jq * 16 + m;
            int ti = i >> 3, tk = i & 7;
            ob[(ti * 64 + pr) * 512 + tk * 64 + c] = acc[jq][r] + c0;
        }
}

extern "C" void kernel_launch(void* const* d_in, const int* in_sizes, int n_in,
                              void* d_out, int out_size, void* d_ws, size_t ws_size,
                              hipStream_t stream) {
    const float* x     = (const float*)d_in[0];
    // d_in[1] = n, d_in[2] = m  (fixed 8 by setup_inputs)
    const float* w1    = (const float*)d_in[3];
    const float* b1    = (const float*)d_in[4];
    const float* wqkv  = (const float*)d_in[5];
    const float* wproj = (const float*)d_in[6];
    const float* bproj = (const float*)d_in[7];
    const float* w2    = (const float*)d_in[8];
    const float* b2    = (const float*)d_in[9];
    float* out = (float*)d_out;
    float* ws  = (float*)d_ws;

    k1_gram<<<128, 256, 0, stream>>>(x, ws);
    k2_attn<<<64, 256, 0, stream>>>(w1, b1, wqkv, wproj, bproj, w2, b2, ws);
    k3_apply<<<512, 256, 0, stream>>>(x, ws, out);
}